// Round 20
// baseline (1714.859 us; speedup 1.0000x reference)
//
#include <hip/hip_runtime.h>

namespace {

constexpr int kT = 256;

typedef _Float16 h2 __attribute__((ext_vector_type(2)));
typedef _Float16 f16x8 __attribute__((ext_vector_type(8)));
typedef float f32x4 __attribute__((ext_vector_type(4)));
typedef unsigned int u32;
typedef u32 u32x4 __attribute__((ext_vector_type(4)));

__device__ __forceinline__ float fast_tanh(float x) {
    float e = __expf(2.0f * x);
    return 1.0f - 2.0f * __builtin_amdgcn_rcpf(e + 1.0f);
}

__device__ __forceinline__ float fdot2(u32 a, u32 b, float c) {
    return __builtin_amdgcn_fdot2(__builtin_bit_cast(h2, a),
                                  __builtin_bit_cast(h2, b), c, false);
}
__device__ __forceinline__ u32 pack_f16(float a, float b) {
    h2 h; h.x = (_Float16)a; h.y = (_Float16)b;
    return __builtin_bit_cast(u32, h);
}

__device__ __forceinline__ float dpp_xor1(float x) {
    return __builtin_bit_cast(float, __builtin_amdgcn_update_dpp(
        0, __builtin_bit_cast(int, x), 0xB1, 0xF, 0xF, true)); // quad [1,0,3,2]
}
__device__ __forceinline__ float dpp_xor2(float x) {
    return __builtin_bit_cast(float, __builtin_amdgcn_update_dpp(
        0, __builtin_bit_cast(int, x), 0x4E, 0xF, 0xF, true)); // quad [2,3,0,1]
}
__device__ __forceinline__ float dpp_ror8(float x) {           // lane ^ 8 within row16
    return __builtin_bit_cast(float, __builtin_amdgcn_update_dpp(
        0, __builtin_bit_cast(int, x), 0x128, 0xF, 0xF, true)); // row_ror:8
}
template <int PAT>
__device__ __forceinline__ float swz(float x) {
    return __builtin_bit_cast(float,
        __builtin_amdgcn_ds_swizzle(__builtin_bit_cast(int, x), PAT));
}
__device__ __forceinline__ float read_lane(float x, int lane) {
    return __builtin_bit_cast(float,
        __builtin_amdgcn_readlane(__builtin_bit_cast(int, x), lane));
}

// MFMA hidden layers: h stored as [4 rows][136 f16], row stride 68 u32
// words (word j holds f16 cols 2j, 2j+1). ONLY the 4 real batch rows live
// in LDS (r20 change): A rows 4-15 of the padded 16x128x128 GEMM enter as
// REGISTER ZEROS -- C[r][*] depends only on A row r, so pad-row content
// never touches real outputs. Lanes with m16 >= 4 skip the ds_read
// entirely: A-read traffic drops 4x (256B/read = ~2 LDS phases vs 8),
// which was ~85% of the layer-phase LDS budget in r19 (SQ_LDS_BANK_
// CONFLICT 1e8 from 64-distinct-address b128 reads of a mostly-zero tile).
// Per layer, wave w computes N-tile cols 16w..16w+15 as 4 K-step
// v_mfma_f32_16x16x32_f16 (f32 accumulate). A-frag (refcheck-verified
// r19): row=l&15, k=8*(l>>4)+e. C (m89-verified): col=lane&15,
// row=(lane>>4)*4+reg -> lanes 0-15 hold all real rows; they apply
// bias+tanh and write 4 ds_write_b16 each (<=2-way banks, free).
//
// STRUCTURAL LEDGER (hard-won; r = round):
//  * 512-thread block = 8 waves = 2 waves/SIMD ALWAYS -> hard 128 VGPR cap.
//    TERMINALLY DEAD: f4-quad f32 weight/acc shapes (r1/r2/r5), k-major
//    row-fast layouts (r9/r10/r13) -- spill wholesale (128-pin + GB-scale
//    scratch FETCH). wgtB (12 quad-aligned f16x8) fits at 76 VGPR (r19).
//  * Occupancy is NOT a lever: a 2nd block/CU never co-resides (r7).
//  * Barrier count minimal at 4/dyn (input->L0->L1->L2->output chain).
//  * Output layer: packed fdot2 + XOR-permuted reduce-scatter + folded
//    b_out (r17/r18).
//  * f16 numerics: products exact (f32 acc); absmax 0.125 vs thr 0.345.
//  * LDS index maps MUST be checked injective before landing (r12).
__global__ __launch_bounds__(512, 1) void hybrid_ode_kernel(
    const float* __restrict__ y0,
    const float* __restrict__ t_span,
    const float* __restrict__ meal,
    const float* __restrict__ tvns,
    const float* __restrict__ W_in, const float* __restrict__ b_in,
    const float* __restrict__ W_h,  const float* __restrict__ b_h,
    const float* __restrict__ W_out,const float* __restrict__ b_out,
    float* __restrict__ out)
{
    const int tid = threadIdx.x;
    const int w   = tid >> 6;          // wave 0..7
    const int l   = tid & 63;
    const int m16 = l & 15;            // A-row / C-col index within tile
    const int g4  = l >> 4;            // lane group 0..3
    const int rw  = w & 3;             // batch row this wave carries
    const int row = blockIdx.x * 4 + rw;
    const bool lanelo = (g4 == 0);     // lanes holding real C rows 0..3
    const bool arow   = (m16 < 4);     // lanes whose A-row is real

    __shared__ __align__(16) u32 hp0[272];   // 4 rows x 68 words
    __shared__ __align__(16) u32 hp1[272];

    // ---- MFMA B-fragment staging: wgtB[ll][ks] = W_h[k][col] f16-packed,
    // col = 16w + m16, k = 32*ks + 8*g4 + e (e=0..7).
    f16x8 wgtB[3][4];
    const int colB = 16 * w + m16;
    #pragma unroll
    for (int ll = 0; ll < 3; ++ll)
        #pragma unroll
        for (int ks = 0; ks < 4; ++ks) {
            const int k0 = 32 * ks + 8 * g4;
            f16x8 bv;
            #pragma unroll
            for (int e = 0; e < 8; ++e)
                bv[e] = (_Float16)W_h[(size_t)(ll * 128 + k0 + e) * 128 + colB];
            wgtB[ll][ks] = bv;
        }
    float bhB[3];
    #pragma unroll
    for (int ll = 0; ll < 3; ++ll) bhB[ll] = b_h[ll * 128 + colB];

    // A-fragment read base (words): row m16 (<4 only), k-offset 8*g4
    const int abase = m16 * 68 + 4 * g4;
    // C write-back (lanes 0-15): col j = 16w + m16 -> word 8w + (m16>>1),
    // half m16&1, rows r=0..3 at +68r words (136 halfwords).
    const int cwhalf = 2 * (8 * w + (m16 >> 1)) + (m16 & 1);

    // Input layer register-direct: wave w covers row rw, cols
    // j2 = l + 64*(w>>2); f16 write at word rw*68 + (j2>>1), half j2&1.
    const int j2 = l + 64 * (w >> 2);
    const int whalf2 = 2 * (rw * 68 + (j2 >> 1)) + (j2 & 1);
    float win[8];
    win[0] = W_in[0 * 128 + j2];                         // t
    win[1] = W_in[1 * 128 + j2];                         // y0
    win[2] = W_in[2 * 128 + j2];                         // y1
    win[3] = W_in[3 * 128 + j2];                         // y2
    win[4] = W_in[4 * 128 + j2] + W_in[7 * 128 + j2];    // y3 (+ glp1=y3)
    win[5] = W_in[5 * 128 + j2];                         // y4
    win[6] = W_in[6 * 128 + j2];                         // y5
    win[7] = W_in[8 * 128 + j2];                         // v
    const float bin = b_in[j2];

    // output layer: XOR-permuted PACKED weights (r18); b_out folded.
    const int s8 = l & 7;
    u32 wop[8];
    #pragma unroll
    for (int p = 0; p < 8; ++p) {
        const int q = p ^ s8;
        wop[p] = (q < 6) ? pack_f16(W_out[l * 6 + q], W_out[(l + 64) * 6 + q])
                         : 0u;
    }
    const float bo_own = (s8 < 6) ? b_out[s8] : 0.0f;
    // h3 reads (f16) for row rw at cols l and l+64
    const int oA = 2 * (rw * 68 + (l >> 1)) + (l & 1);
    const int oB = oA + 64;            // +32 words

    float y[6];
    #pragma unroll
    for (int s = 0; s < 6; ++s) y[s] = y0[row * 6 + s];

    if (w < 4 && l == 0) {
        #pragma unroll
        for (int s = 0; s < 6; ++s) out[(size_t)row * kT * 6 + s] = y[s];
    }

    const float* mrow = meal + (size_t)row * kT;
    const float* vrow = tvns + (size_t)row * kT;

    auto dyn = [&](float t, const float* yc, float m, float v, float* d) {
        // ---- input layer 9->128, register-direct.
        {
            float s = bin + t * win[0];
            s += yc[0] * win[1] + yc[1] * win[2] + yc[2] * win[3];
            s += yc[3] * win[4] + yc[4] * win[5] + yc[5] * win[6];
            s += v * win[7];
            const float hv = fast_tanh(s);
            ((unsigned short*)hp0)[whalf2] =
                __builtin_bit_cast(unsigned short, (_Float16)hv);
        }
        __syncthreads();

        // ---- 3 hidden layers 128->128 via MFMA (padded M=16, 4 rows real;
        // pad rows enter as register zeros -- no LDS traffic for them)
        #pragma unroll
        for (int ll = 0; ll < 3; ++ll) {
            const u32* rb = (ll & 1) ? hp1 : hp0;
            u32*       wb = (ll & 1) ? hp0 : hp1;

            f32x4 cacc = {0.0f, 0.0f, 0.0f, 0.0f};
            #pragma unroll
            for (int ks = 0; ks < 4; ++ks) {
                u32x4 aw = {0u, 0u, 0u, 0u};
                if (arow) aw = *(const u32x4*)(rb + abase + 16 * ks);
                cacc = __builtin_amdgcn_mfma_f32_16x16x32_f16(
                    __builtin_bit_cast(f16x8, aw), wgtB[ll][ks], cacc, 0, 0, 0);
            }
            if (lanelo) {
                #pragma unroll
                for (int r = 0; r < 4; ++r) {
                    const float hv = fast_tanh(cacc[r] + bhB[ll]);
                    ((unsigned short*)wb)[cwhalf + 136 * r] =
                        __builtin_bit_cast(unsigned short, (_Float16)hv);
                }
            }
            __syncthreads();
        }

        // ---- output layer 128->6 for this wave's row; h3 (f16) in hp1.
        const unsigned short* h3u = (const unsigned short*)hp1;
        const u32 hq = (u32)h3u[oA] | ((u32)h3u[oB] << 16);
        float P[8];
        #pragma unroll
        for (int p = 0; p < 8; ++p) P[p] = fdot2(hq, wop[p], 0.0f);
        float Q[4];
        #pragma unroll
        for (int i = 0; i < 4; ++i) Q[i] = P[2*i] + dpp_xor1(P[2*i+1]);
        const float R0 = Q[0] + dpp_xor2(Q[1]);
        const float R1 = Q[2] + dpp_xor2(Q[3]);
        float S = R0 + swz<0x101F>(R1);   // xor4
        S += dpp_ror8(S);                 // xor8
        S += swz<0x401F>(S);              // xor16
        S += __shfl_xor(S, 32);           // xor32
        S += bo_own;                      // fold b_out pre-broadcast

        const float p0 = read_lane(S, 0);
        const float p1 = read_lane(S, 1);
        const float p2 = read_lane(S, 2);
        const float p3 = read_lane(S, 3);
        const float p4 = read_lane(S, 4);
        const float p5 = read_lane(S, 5);

        const float G = yc[0], I = yc[1], N = yc[2], L = yc[3], GE = yc[4], F = yc[5];
        d[0] = -0.01f*I*G + 0.05f*GE                                    + p0;
        d[1] = (G/(100.0f+G))*(1.0f + 2.0f*L/(5.0f+L)) - 0.1f*I         + p1;
        d[2] = -0.05f*N                                                 + p2;
        d[3] = 0.05f*GE - 0.2f*L                                        + p3;
        d[4] = m - 0.05f*GE                                             + p4;
        d[5] = -0.01f*I*F                                               + p5;
    };

    for (int i = 0; i < kT - 1; ++i) {
        const float t0 = t_span[i], t1 = t_span[i + 1];
        const float dt = t1 - t0;
        const float m0 = mrow[i], m1 = mrow[i + 1];
        const float v0 = vrow[i], v1 = vrow[i + 1];
        const float tm = t0 + 0.5f * dt;
        const float mm = 0.5f * (m0 + m1), vm = 0.5f * (v0 + v1);

        float d[6], ksum[6], yc[6];

        dyn(t0, y, m0, v0, d);
        #pragma unroll
        for (int s = 0; s < 6; ++s) { ksum[s] = d[s]; yc[s] = y[s] + 0.5f * dt * d[s]; }
        dyn(tm, yc, mm, vm, d);
        #pragma unroll
        for (int s = 0; s < 6; ++s) { ksum[s] += 2.0f * d[s]; yc[s] = y[s] + 0.5f * dt * d[s]; }
        dyn(tm, yc, mm, vm, d);
        #pragma unroll
        for (int s = 0; s < 6; ++s) { ksum[s] += 2.0f * d[s]; yc[s] = y[s] + dt * d[s]; }
        dyn(t1, yc, m1, v1, d);
        #pragma unroll
        for (int s = 0; s < 6; ++s) {
            ksum[s] += d[s];
            y[s] += (dt * (1.0f / 6.0f)) * ksum[s];
        }

        if (w < 4 && l == 0) {
            #pragma unroll
            for (int s = 0; s < 6; ++s)
                out[((size_t)row * kT + (i + 1)) * 6 + s] = y[s];
        }
    }
}

} // namespace

extern "C" void kernel_launch(void* const* d_in, const int* in_sizes, int n_in,
                              void* d_out, int out_size, void* d_ws, size_t ws_size,
                              hipStream_t stream) {
    const float* y0     = (const float*)d_in[0];
    const float* t_span = (const float*)d_in[1];
    const float* meal   = (const float*)d_in[2];
    const float* tvns   = (const float*)d_in[3];
    const float* W_in   = (const float*)d_in[4];
    const float* b_in   = (const float*)d_in[5];
    const float* W_h    = (const float*)d_in[6];
    const float* b_h    = (const float*)d_in[7];
    const float* W_out  = (const float*)d_in[8];
    const float* b_out  = (const float*)d_in[9];
    float* out          = (float*)d_out;

    hipLaunchKernelGGL(hybrid_ode_kernel, dim3(256), dim3(512), 0, stream,
                       y0, t_span, meal, tvns,
                       W_in, b_in, W_h, b_h, W_out, b_out, out);
}